// Round 7
// baseline (201.538 us; speedup 1.0000x reference)
//
#include <hip/hip_runtime.h>
#include <hip/hip_bf16.h>

// B=8 N=1024 C=768 H=12 D=64.  All MFMA: v_mfma_f32_16x16x32_bf16.
// Frag layouts (verified): A: m=lane&15, k=quad*8+j ; B: n=lane&15, k=quad*8+j ;
// C/D: col=lane&15, row=quad*4+reg.
//
// Attention: S^T = K·Q^T (A=K, B=Q) -> C-layout has q on lanes, keys on regs.
// PV uses a PERMUTED contraction index k = bits[n1 q1 q0 n0 c e] of key
// (key bits [n1 n0 q1 q0 c e]). Under this permutation the packed exp(S^T)
// registers ARE the PV B-fragments (no LDS round-trip, no shuffles). V's
// columns are stored pre-permuted by gemm_qkv's epilogue. K/V tiles staged to
// LDS via global_load_lds double-buffering.
// R7: 64 q per wave, 128-thread blocks (2 waves) -> total waves halve, LDS
// read pipe (the 58% cost at R6) halves; MFMA per ds_read doubles to 4.5.
// Softmax uses fixed max 0 (scores bounded ~2^20 in exp2 domain; num/denom
// share bf16 P so scaling cancels). temp*log2e is pre-folded into q.
//
// LDS tiles: stride-64 shorts, XOR swizzle (row,chunk)->row*64+((chunk^(row&7))<<3);
// keeps global_load_lds legal (wave-uniform dst), caps ds conflicts at 2-way (free).

typedef __attribute__((ext_vector_type(8))) short bf16x8;
typedef __attribute__((ext_vector_type(4))) float f32x4;

__device__ __forceinline__ unsigned short f2bf(float f) {
    union { float f; unsigned u; } v; v.f = f;
    unsigned r = v.u + 0x7fff + ((v.u >> 16) & 1);   // RNE
    return (unsigned short)(r >> 16);
}

__device__ __forceinline__ unsigned pack2(float a, float b) {
    union { __hip_bfloat162 h; unsigned u; } c;
    c.h = __float22bfloat162_rn(make_float2(a, b));   // .x -> low short
    return c.u;
}

__device__ __forceinline__ void gl_lds16(const unsigned short* g, unsigned short* l) {
    __builtin_amdgcn_global_load_lds(
        (const __attribute__((address_space(1))) void*)g,
        (__attribute__((address_space(3))) void*)l, 16, 0, 0);
}

__device__ __forceinline__ bf16x8 rd_sw(const unsigned short* lds, int row, int chunk) {
    return *(const bf16x8*)&lds[row * 64 + (((chunk ^ (row & 7))) << 3)];
}

// stage a 64-row x 64-short tile into swizzled LDS — 256-thread version
__device__ __forceinline__ void stage64(const unsigned short* g, int gstride,
                                        unsigned short* lds, int t) {
    int row0 = t >> 3, c = t & 7;
    #pragma unroll
    for (int r = 0; r < 2; r++) {
        int row = r * 32 + row0;
        gl_lds16(g + (size_t)row * gstride + ((c ^ (row & 7)) << 3),
                 lds + r * 2048 + ((t >> 6) << 9));   // wave-uniform base; HW adds lane*16B
    }
}

// stage a 64-row x 64-short tile into swizzled LDS — 128-thread version
__device__ __forceinline__ void stage64h(const unsigned short* g, int gstride,
                                         unsigned short* lds, int t) {
    int row0 = t >> 3, c = t & 7;   // row0 0..15 across the 2 waves
    #pragma unroll
    for (int r = 0; r < 4; r++) {
        int row = r * 16 + row0;
        gl_lds16(g + (size_t)row * gstride + ((c ^ (row & 7)) << 3),
                 lds + r * 1024 + ((t >> 6) << 9));
    }
}

// ---------------- fused prep: pack x + transpose both weights ----------------
__global__ void prep(const float* __restrict__ x, const float* __restrict__ w_qkv,
                     const float* __restrict__ w_proj,
                     unsigned short* __restrict__ xb, unsigned short* __restrict__ wqkvT,
                     unsigned short* __restrict__ wprojT) {
    int b = blockIdx.x, t = threadIdx.x;
    if (b < 6144) {                       // pack x: 6144*256 float4s
        int i = b * 256 + t;
        float4 v = ((const float4*)x)[i];
        ushort4 o;
        o.x = f2bf(v.x); o.y = f2bf(v.y); o.z = f2bf(v.z); o.w = f2bf(v.w);
        ((ushort4*)xb)[i] = o;
        return;
    }
    const float* src; unsigned short* dst; int R, C, bx, by;
    if (b < 6576) { int b2 = b - 6144; src = w_qkv; dst = wqkvT; R = 768; C = 2304; bx = b2 % 36; by = b2 / 36; }
    else          { int b3 = b - 6576; src = w_proj; dst = wprojT; R = 768; C = 768;  bx = b3 % 12; by = b3 / 12; }
    __shared__ float tile[64][65];
    int c0 = bx * 64, r0 = by * 64;
    int tr = t >> 4, tc4 = (t & 15) * 4;
    #pragma unroll
    for (int p = 0; p < 4; p++) {
        int r = tr + p * 16;
        float4 v = *(const float4*)&src[(size_t)(r0 + r) * C + c0 + tc4];
        tile[r][tc4 + 0] = v.x; tile[r][tc4 + 1] = v.y;
        tile[r][tc4 + 2] = v.z; tile[r][tc4 + 3] = v.w;
    }
    __syncthreads();
    #pragma unroll
    for (int p = 0; p < 4; p++) {
        int rr = tr + p * 16;
        ushort4 o;
        o.x = f2bf(tile[tc4 + 0][rr]);
        o.y = f2bf(tile[tc4 + 1][rr]);
        o.z = f2bf(tile[tc4 + 2][rr]);
        o.w = f2bf(tile[tc4 + 3][rr]);
        *(ushort4*)&dst[(size_t)(c0 + rr) * R + r0 + tc4] = o;
    }
}

// ---------------- QKV GEMM: (8192x768)@(768x2304) -> scatter q,k,vT bf16 ----------------
// q is pre-scaled by temp[h]*log2(e); vT columns are stored k-permuted (see header).
__global__ __launch_bounds__(256, 2)
void gemm_qkv(const unsigned short* __restrict__ xb, const unsigned short* __restrict__ wT,
              const float* __restrict__ bias, const float* __restrict__ temp,
              unsigned short* __restrict__ qb, unsigned short* __restrict__ kb,
              unsigned short* __restrict__ vb) {
    const int K = 768;
    __shared__ unsigned short As[8192];   // 128 x 64 swizzled
    __shared__ unsigned short Bs[8192];
    int t = threadIdx.x;
    int m0 = blockIdx.x * 128;
    int n0 = blockIdx.y * 128;
    int w = t >> 6, lane = t & 63, l16 = lane & 15, quad = lane >> 4;
    int wm = w >> 1, wn = w & 1;
    const f32x4 zero4 = {0.f, 0.f, 0.f, 0.f};
    f32x4 acc[4][4];
    #pragma unroll
    for (int a = 0; a < 4; a++)
        #pragma unroll
        for (int b = 0; b < 4; b++) acc[a][b] = zero4;

    int row0 = t >> 3, ch = t & 7;
    const unsigned short* gA = xb + (size_t)m0 * K;
    const unsigned short* gB = wT + (size_t)n0 * K;

    for (int k0 = 0; k0 < K; k0 += 64) {
        __syncthreads();
        #pragma unroll
        for (int r = 0; r < 4; r++) {
            int row = r * 32 + row0;
            int gc = k0 + ((ch ^ (row & 7)) << 3);
            gl_lds16(gA + (size_t)row * K + gc, As + r * 2048 + ((t >> 6) << 9));
            gl_lds16(gB + (size_t)row * K + gc, Bs + r * 2048 + ((t >> 6) << 9));
        }
        __syncthreads();
        #pragma unroll
        for (int ks = 0; ks < 2; ks++) {
            bf16x8 af[4], bf[4];
            #pragma unroll
            for (int mi = 0; mi < 4; mi++)
                af[mi] = rd_sw(As, wm * 64 + mi * 16 + l16, ks * 4 + quad);
            #pragma unroll
            for (int ni = 0; ni < 4; ni++)
                bf[ni] = rd_sw(Bs, wn * 64 + ni * 16 + l16, ks * 4 + quad);
            #pragma unroll
            for (int mi = 0; mi < 4; mi++)
                #pragma unroll
                for (int ni = 0; ni < 4; ni++)
                    acc[mi][ni] = __builtin_amdgcn_mfma_f32_16x16x32_bf16(af[mi], bf[ni], acc[mi][ni], 0, 0, 0);
        }
    }

    // epilogue: col n = seg*768 + h*64 + d
    int nb = n0 + wn * 64;
    int seg = nb / 768;
    int nc = nb % 768;
    int h = nc >> 6;
    int bb = m0 >> 10;
    int bh = bb * 12 + h;
    float bv[4];
    #pragma unroll
    for (int ni = 0; ni < 4; ni++) bv[ni] = bias[nb + ni * 16 + l16];

    if (seg < 2) {
        unsigned short* dst = (seg == 0) ? qb : kb;
        float scale = (seg == 0) ? temp[h] * 1.44269504088896f : 1.0f;
        #pragma unroll
        for (int mi = 0; mi < 4; mi++) {
            int nrow_base = (m0 & 1023) + wm * 64 + mi * 16 + quad * 4;
            #pragma unroll
            for (int i = 0; i < 4; i++) {
                unsigned short* drow = dst + ((size_t)bh * 1024 + nrow_base + i) * 64;
                #pragma unroll
                for (int ni = 0; ni < 4; ni++)
                    drow[ni * 16 + l16] = f2bf((acc[mi][ni][i] + bv[ni]) * scale);
            }
        }
    } else {
        #pragma unroll
        for (int mi = 0; mi < 4; mi++) {
            int nrow0 = (m0 & 1023) + wm * 64 + mi * 16 + quad * 4;
            // k-permuted column: key bits [n1 n0 q1 q0 c e] -> col bits [n1 q1 q0 n0 c e]
            int nl = nrow0 & 63;
            int ncol = (nrow0 & 960) + (nl & 32) + ((nl & 12) << 1) + ((nl & 16) >> 2);
            #pragma unroll
            for (int ni = 0; ni < 4; ni++) {
                int d = ni * 16 + l16;
                ushort4 pk;
                pk.x = f2bf(acc[mi][ni][0] + bv[ni]);
                pk.y = f2bf(acc[mi][ni][1] + bv[ni]);
                pk.z = f2bf(acc[mi][ni][2] + bv[ni]);
                pk.w = f2bf(acc[mi][ni][3] + bv[ni]);
                *(ushort4*)&vb[((size_t)bh * 64 + d) * 1024 + ncol] = pk;
            }
        }
    }
}

// ---------------- flash attention: 128 q/block, 64 q/wave (2 waves), register-only P ----
// grid (96, 8), block 128: blockIdx.x = b*12+h fast dim -> (b,h)'s q-blocks share XCD L2.
__global__ __launch_bounds__(128, 2)
void attn_kernel(const unsigned short* __restrict__ qb, const unsigned short* __restrict__ kb,
                 const unsigned short* __restrict__ vb,
                 unsigned short* __restrict__ attn) {
    __shared__ unsigned short Kt[2][4096];   // 64 keys x 64 d, swizzled
    __shared__ unsigned short Vt[2][4096];   // 64 d x 64 k(perm), swizzled
    int t = threadIdx.x, w = t >> 6, lane = t & 63, l16 = lane & 15, quad = lane >> 4;
    int bh = blockIdx.x, qblk = blockIdx.y;
    int bb = bh / 12, h = bh % 12;
    int qbase = qblk * 128 + w * 64;         // wave's 64-q base within (b,h)

    const unsigned short* kbase = kb + (size_t)bh * 65536;
    const unsigned short* vbase = vb + (size_t)bh * 65536;

    stage64h(kbase, 64, Kt[0], t);
    stage64h(vbase, 1024, Vt[0], t);

    // Q B-frags (pre-scaled by temp*log2e): qh in {0..3}, d-halves
    bf16x8 bq[4][2];
    #pragma unroll
    for (int qh = 0; qh < 4; qh++) {
        const unsigned short* qrow = qb + ((size_t)bh * 1024 + qbase + qh * 16 + l16) * 64;
        bq[qh][0] = *(const bf16x8*)&qrow[quad * 8];
        bq[qh][1] = *(const bf16x8*)&qrow[32 + quad * 8];
    }

    bf16x8 aone;
    #pragma unroll
    for (int j = 0; j < 8; j++) aone[j] = (short)0x3F80;   // bf16 1.0

    const f32x4 zero4 = {0.f, 0.f, 0.f, 0.f};
    f32x4 Oacc[4][4];     // [qh][ti] O^T: rows=d, cols=q
    f32x4 Osum[4];
    #pragma unroll
    for (int qh = 0; qh < 4; qh++) {
        Osum[qh] = zero4;
        #pragma unroll
        for (int ti = 0; ti < 4; ti++) Oacc[qh][ti] = zero4;
    }

    int ktd = qbase >> 6;                    // kt tile containing this wave's diagonal
    bool eq[4];
    #pragma unroll
    for (int i = 0; i < 4; i++) eq[i] = (l16 == quad * 4 + i);

    for (int kt = 0; kt < 16; kt++) {
        int cur = kt & 1;
        __syncthreads();                     // prefetch(kt) drained; prev reads done
        if (kt < 15) {
            stage64h(kbase + (size_t)(kt + 1) * 4096, 64, Kt[cur ^ 1], t);
            stage64h(vbase + (size_t)(kt + 1) * 64, 1024, Vt[cur ^ 1], t);
        }
        const unsigned short* Kc = Kt[cur];
        const unsigned short* Vc = Vt[cur];

        // S^T per ni (16 keys) x 4 q-halves; exp2 inline; pack straight into
        // the PV B-frag unions (registers only).
        union { unsigned u[4]; bf16x8 b; } pt[4][2];
        #pragma unroll
        for (int ni = 0; ni < 4; ni++) {
            bf16x8 ak0 = rd_sw(Kc, ni * 16 + l16, quad);
            bf16x8 ak1 = rd_sw(Kc, ni * 16 + l16, 4 + quad);
            #pragma unroll
            for (int qh = 0; qh < 4; qh++) {
                f32x4 z = zero4;
                z = __builtin_amdgcn_mfma_f32_16x16x32_bf16(ak0, bq[qh][0], z, 0, 0, 0);
                z = __builtin_amdgcn_mfma_f32_16x16x32_bf16(ak1, bq[qh][1], z, 0, 0, 0);
                float p0 = exp2f(z[0]);
                float p1 = exp2f(z[1]);
                float p2 = exp2f(z[2]);
                float p3 = exp2f(z[3]);
                // diagonal: key = kt*64+ni*16+quad*4+i, q = qbase+qh*16+l16;
                // equality only possible when kt==ktd && ni==qh (uniform branch)
                if (kt == ktd && ni == qh) {
                    if (eq[0]) p0 = 0.f;
                    if (eq[1]) p1 = 0.f;
                    if (eq[2]) p2 = 0.f;
                    if (eq[3]) p3 = 0.f;
                }
                pt[qh][ni >> 1].u[(ni & 1) * 2 + 0] = pack2(p0, p1);
                pt[qh][ni >> 1].u[(ni & 1) * 2 + 1] = pack2(p2, p3);
            }
        }

        #pragma unroll
        for (int qh = 0; qh < 4; qh++) {
            // denominator: ones x P^T (permutation-invariant)
            Osum[qh] = __builtin_amdgcn_mfma_f32_16x16x32_bf16(aone, pt[qh][0].b, Osum[qh], 0, 0, 0);
            Osum[qh] = __builtin_amdgcn_mfma_f32_16x16x32_bf16(aone, pt[qh][1].b, Osum[qh], 0, 0, 0);
        }

        // O^T += V^T P^T  (V columns pre-permuted to k-order)
        #pragma unroll
        for (int ti = 0; ti < 4; ti++) {
            bf16x8 av0 = rd_sw(Vc, ti * 16 + l16, quad);
            bf16x8 av1 = rd_sw(Vc, ti * 16 + l16, 4 + quad);
            #pragma unroll
            for (int qh = 0; qh < 4; qh++) {
                Oacc[qh][ti] = __builtin_amdgcn_mfma_f32_16x16x32_bf16(av0, pt[qh][0].b, Oacc[qh][ti], 0, 0, 0);
                Oacc[qh][ti] = __builtin_amdgcn_mfma_f32_16x16x32_bf16(av1, pt[qh][1].b, Oacc[qh][ti], 0, 0, 0);
            }
        }
    }

    // epilogue: lane holds q=l16 (per qh), d = ti*16 + quad*4 + i -> ushort4 stores
    #pragma unroll
    for (int qh = 0; qh < 4; qh++) {
        float inv = 1.0f / Osum[qh][0];
        int orow = bb * 1024 + qbase + qh * 16 + l16;
        #pragma unroll
        for (int ti = 0; ti < 4; ti++) {
            union { ushort4 v; unsigned u[2]; } pk4;
            pk4.u[0] = pack2(Oacc[qh][ti][0] * inv, Oacc[qh][ti][1] * inv);
            pk4.u[1] = pack2(Oacc[qh][ti][2] * inv, Oacc[qh][ti][3] * inv);
            int col = h * 64 + ti * 16 + quad * 4;
            *(ushort4*)&attn[(size_t)orow * 768 + col] = pk4.v;
        }
    }
}

// ---------------- proj GEMM: (8192x768)@(768x768) + bias -> fp32 out ----------------
// 64x128 tiles: grid 128x6 = 768 blocks = 3/CU even (was 384 = 1.5/CU, tail-bound).
__global__ __launch_bounds__(256, 2)
void gemm_proj(const unsigned short* __restrict__ ab, const unsigned short* __restrict__ wT,
               const float* __restrict__ bias, float* __restrict__ out) {
    const int K = 768;
    __shared__ unsigned short As[4096];   // 64 x 64 swizzled
    __shared__ unsigned short Bs[8192];   // 128 x 64 swizzled
    int t = threadIdx.x;
    int m0 = blockIdx.x * 64;
    int n0 = blockIdx.y * 128;
    int w = t >> 6, lane = t & 63, l16 = lane & 15, quad = lane >> 4;
    int wm = w >> 1, wn = w & 1;          // wave tile: 32 m x 64 n
    const f32x4 zero4 = {0.f, 0.f, 0.f, 0.f};
    f32x4 acc[2][4];
    #pragma unroll
    for (int a = 0; a < 2; a++)
        #pragma unroll
        for (int b = 0; b < 4; b++) acc[a][b] = zero4;

    int row0 = t >> 3, ch = t & 7;
    const unsigned short* gA = ab + (size_t)m0 * K;
    const unsigned short* gB = wT + (size_t)n0 * K;

    for (int k0 = 0; k0 < K; k0 += 64) {
        __syncthreads();
        #pragma unroll
        for (int r = 0; r < 2; r++) {
            int row = r * 32 + row0;
            int gc = k0 + ((ch ^ (row & 7)) << 3);
            gl_lds16(gA + (size_t)row * K + gc, As + r * 2048 + ((t >> 6) << 9));
        }
        #pragma unroll
        for (int r = 0; r < 4; r++) {
            int row = r * 32 + row0;
            int gc = k0 + ((ch ^ (row & 7)) << 3);
            gl_lds16(gB + (size_t)row * K + gc, Bs + r * 2048 + ((t >> 6) << 9));
        }
        __syncthreads();
        #pragma unroll
        for (int ks = 0; ks < 2; ks++) {
            bf16x8 af[2], bf[4];
            #pragma unroll
            for (int mi = 0; mi < 2; mi++)
                af[mi] = rd_sw(As, wm * 32 + mi * 16 + l16, ks * 4 + quad);
            #pragma unroll
            for (int ni = 0; ni < 4; ni++)
                bf[ni] = rd_sw(Bs, wn * 64 + ni * 16 + l16, ks * 4 + quad);
            #pragma unroll
            for (int mi = 0; mi < 2; mi++)
                #pragma unroll
                for (int ni = 0; ni < 4; ni++)
                    acc[mi][ni] = __builtin_amdgcn_mfma_f32_16x16x32_bf16(af[mi], bf[ni], acc[mi][ni], 0, 0, 0);
        }
    }

    #pragma unroll
    for (int mi = 0; mi < 2; mi++)
        #pragma unroll
        for (int i = 0; i < 4; i++) {
            int row = m0 + wm * 32 + mi * 16 + quad * 4 + i;
            float* orow = out + (size_t)row * 768;
            #pragma unroll
            for (int ni = 0; ni < 4; ni++) {
                int col = n0 + wn * 64 + ni * 16 + l16;
                orow[col] = acc[mi][ni][i] + bias[col];
            }
        }
}

extern "C" void kernel_launch(void* const* d_in, const int* in_sizes, int n_in,
                              void* d_out, int out_size, void* d_ws, size_t ws_size,
                              hipStream_t stream) {
    const float* x      = (const float*)d_in[0];
    const float* w_qkv  = (const float*)d_in[1];
    const float* b_qkv  = (const float*)d_in[2];
    const float* w_proj = (const float*)d_in[3];
    const float* b_proj = (const float*)d_in[4];
    const float* temp   = (const float*)d_in[5];
    float* out = (float*)d_out;

    char* ws = (char*)d_ws;
    unsigned short* xb     = (unsigned short*)(ws);                 // 8192x768 bf16
    unsigned short* wqkvT  = (unsigned short*)(ws + 12582912);      // 2304x768 bf16
    unsigned short* wprojT = (unsigned short*)(ws + 16121856);      // 768x768 bf16
    unsigned short* qb     = (unsigned short*)(ws + 17301504);      // (B H N D) bf16, pre-scaled
    unsigned short* kb     = (unsigned short*)(ws + 29884416);      // (B H N D) bf16
    unsigned short* vb     = (unsigned short*)(ws + 42467328);      // (B H D N) bf16, k-permuted cols
    unsigned short* attn   = (unsigned short*)(ws + 55050240);      // 8192x768 bf16

    prep<<<6720, 256, 0, stream>>>(x, w_qkv, w_proj, xb, wqkvT, wprojT);
    gemm_qkv<<<dim3(64, 18), 256, 0, stream>>>(xb, wqkvT, b_qkv, temp, qb, kb, vb);
    attn_kernel<<<dim3(96, 8), 128, 0, stream>>>(qb, kb, vb, attn);
    gemm_proj<<<dim3(128, 6), 256, 0, stream>>>(attn, wprojT, b_proj, out);
}

// Round 8
// 189.155 us; speedup vs baseline: 1.0655x; 1.0655x over previous
//
#include <hip/hip_runtime.h>
#include <hip/hip_bf16.h>

// B=8 N=1024 C=768 H=12 D=64.  All MFMA: v_mfma_f32_16x16x32_bf16.
// Frag layouts (verified): A: m=lane&15, k=quad*8+j ; B: n=lane&15, k=quad*8+j ;
// C/D: col=lane&15, row=quad*4+reg.
//
// Attention (R6 config, measured 53 us): S^T = K·Q^T, 32 q/wave, 256-thr blocks.
// PV uses a PERMUTED contraction index k = bits[n1 q1 q0 n0 c e] of key
// (key bits [n1 n0 q1 q0 c e]). Under this permutation the packed exp(S^T)
// registers ARE the PV B-fragments (no LDS round-trip, no shuffles). V's
// columns are stored pre-permuted by gemm_qkv's epilogue. K/V staged to LDS
// via global_load_lds double-buffering. Softmax uses fixed max 0 (scores
// bounded ~2^36 in exp2 domain; num/denom share bf16 P so scaling cancels).
// temp*log2e is pre-folded into q.
//
// gemm_qkv (R8): q/k column-blocks compute C^T (A=w, B=x) so each lane's acc
// holds 4 consecutive d-features -> 16 ushort4 stores instead of 64 scalar
// b16 scatters. v blocks keep normal orientation (ushort4 via permuted cols).
// seg is block-uniform (n0 multiples of 128, boundaries at 768/1536).
//
// LDS tiles: stride-64 shorts, XOR swizzle (row,chunk)->row*64+((chunk^(row&7))<<3);
// keeps global_load_lds legal (wave-uniform dst), caps ds conflicts at 2-way (free).

typedef __attribute__((ext_vector_type(8))) short bf16x8;
typedef __attribute__((ext_vector_type(4))) float f32x4;

__device__ __forceinline__ unsigned short f2bf(float f) {
    union { float f; unsigned u; } v; v.f = f;
    unsigned r = v.u + 0x7fff + ((v.u >> 16) & 1);   // RNE
    return (unsigned short)(r >> 16);
}

__device__ __forceinline__ unsigned pack2(float a, float b) {
    union { __hip_bfloat162 h; unsigned u; } c;
    c.h = __float22bfloat162_rn(make_float2(a, b));   // .x -> low short
    return c.u;
}

__device__ __forceinline__ void gl_lds16(const unsigned short* g, unsigned short* l) {
    __builtin_amdgcn_global_load_lds(
        (const __attribute__((address_space(1))) void*)g,
        (__attribute__((address_space(3))) void*)l, 16, 0, 0);
}

__device__ __forceinline__ bf16x8 rd_sw(const unsigned short* lds, int row, int chunk) {
    return *(const bf16x8*)&lds[row * 64 + (((chunk ^ (row & 7))) << 3)];
}

// stage a 64-row x 64-short tile (row stride gstride shorts) into swizzled LDS (8KB)
__device__ __forceinline__ void stage64(const unsigned short* g, int gstride,
                                        unsigned short* lds, int t) {
    int row0 = t >> 3, c = t & 7;
    #pragma unroll
    for (int r = 0; r < 2; r++) {
        int row = r * 32 + row0;
        gl_lds16(g + (size_t)row * gstride + ((c ^ (row & 7)) << 3),
                 lds + r * 2048 + ((t >> 6) << 9));   // wave-uniform base; HW adds lane*16B
    }
}

// ---------------- fused prep: pack x + transpose both weights ----------------
__global__ void prep(const float* __restrict__ x, const float* __restrict__ w_qkv,
                     const float* __restrict__ w_proj,
                     unsigned short* __restrict__ xb, unsigned short* __restrict__ wqkvT,
                     unsigned short* __restrict__ wprojT) {
    int b = blockIdx.x, t = threadIdx.x;
    if (b < 6144) {                       // pack x: 6144*256 float4s
        int i = b * 256 + t;
        float4 v = ((const float4*)x)[i];
        ushort4 o;
        o.x = f2bf(v.x); o.y = f2bf(v.y); o.z = f2bf(v.z); o.w = f2bf(v.w);
        ((ushort4*)xb)[i] = o;
        return;
    }
    const float* src; unsigned short* dst; int R, C, bx, by;
    if (b < 6576) { int b2 = b - 6144; src = w_qkv; dst = wqkvT; R = 768; C = 2304; bx = b2 % 36; by = b2 / 36; }
    else          { int b3 = b - 6576; src = w_proj; dst = wprojT; R = 768; C = 768;  bx = b3 % 12; by = b3 / 12; }
    __shared__ float tile[64][65];
    int c0 = bx * 64, r0 = by * 64;
    int tr = t >> 4, tc4 = (t & 15) * 4;
    #pragma unroll
    for (int p = 0; p < 4; p++) {
        int r = tr + p * 16;
        float4 v = *(const float4*)&src[(size_t)(r0 + r) * C + c0 + tc4];
        tile[r][tc4 + 0] = v.x; tile[r][tc4 + 1] = v.y;
        tile[r][tc4 + 2] = v.z; tile[r][tc4 + 3] = v.w;
    }
    __syncthreads();
    #pragma unroll
    for (int p = 0; p < 4; p++) {
        int rr = tr + p * 16;
        ushort4 o;
        o.x = f2bf(tile[tc4 + 0][rr]);
        o.y = f2bf(tile[tc4 + 1][rr]);
        o.z = f2bf(tile[tc4 + 2][rr]);
        o.w = f2bf(tile[tc4 + 3][rr]);
        *(ushort4*)&dst[(size_t)(c0 + rr) * R + r0 + tc4] = o;
    }
}

// ---------------- QKV GEMM: (8192x768)@(768x2304) -> scatter q,k,vT bf16 ----------------
// q is pre-scaled by temp[h]*log2(e); vT columns are stored k-permuted (see header).
__global__ __launch_bounds__(256, 2)
void gemm_qkv(const unsigned short* __restrict__ xb, const unsigned short* __restrict__ wT,
              const float* __restrict__ bias, const float* __restrict__ temp,
              unsigned short* __restrict__ qb, unsigned short* __restrict__ kb,
              unsigned short* __restrict__ vb) {
    const int K = 768;
    __shared__ unsigned short As[8192];   // 128 tokens x 64 k, swizzled
    __shared__ unsigned short Bs[8192];   // 128 features x 64 k, swizzled
    int t = threadIdx.x;
    int m0 = blockIdx.x * 128;            // token block
    int n0 = blockIdx.y * 128;            // feature block
    int w = t >> 6, lane = t & 63, l16 = lane & 15, quad = lane >> 4;
    const f32x4 zero4 = {0.f, 0.f, 0.f, 0.f};
    f32x4 acc[4][4];
    #pragma unroll
    for (int a = 0; a < 4; a++)
        #pragma unroll
        for (int b = 0; b < 4; b++) acc[a][b] = zero4;

    int row0 = t >> 3, ch = t & 7;
    const unsigned short* gA = xb + (size_t)m0 * K;
    const unsigned short* gB = wT + (size_t)n0 * K;

    int seg = n0 / 768;                   // block-uniform (0=q, 1=k, 2=v)
    int bb = m0 >> 10;

    if (seg < 2) {
        // -------- transposed orientation: C^T (A=w features, B=x tokens) --------
        int wf = w >> 1, wt = w & 1;      // feature half / token half
        for (int k0 = 0; k0 < K; k0 += 64) {
            __syncthreads();
            #pragma unroll
            for (int r = 0; r < 4; r++) {
                int row = r * 32 + row0;
                int gc = k0 + ((ch ^ (row & 7)) << 3);
                gl_lds16(gA + (size_t)row * K + gc, As + r * 2048 + ((t >> 6) << 9));
                gl_lds16(gB + (size_t)row * K + gc, Bs + r * 2048 + ((t >> 6) << 9));
            }
            __syncthreads();
            #pragma unroll
            for (int ks = 0; ks < 2; ks++) {
                bf16x8 af[4], bf[4];
                #pragma unroll
                for (int mi = 0; mi < 4; mi++)                  // A = w (features)
                    af[mi] = rd_sw(Bs, wf * 64 + mi * 16 + l16, ks * 4 + quad);
                #pragma unroll
                for (int ni = 0; ni < 4; ni++)                  // B = x (tokens)
                    bf[ni] = rd_sw(As, wt * 64 + ni * 16 + l16, ks * 4 + quad);
                #pragma unroll
                for (int mi = 0; mi < 4; mi++)
                    #pragma unroll
                    for (int ni = 0; ni < 4; ni++)
                        acc[mi][ni] = __builtin_amdgcn_mfma_f32_16x16x32_bf16(af[mi], bf[ni], acc[mi][ni], 0, 0, 0);
            }
        }
        // epilogue: lane holds feature = fbase + mi*16 + quad*4 + i, token = ... + l16
        int fbase = n0 + wf * 64;          // multiple of 64 -> one head
        int h = (fbase % 768) >> 6;
        int bh = bb * 12 + h;
        unsigned short* dst = (seg == 0) ? qb : kb;
        float scale = (seg == 0) ? temp[h] * 1.44269504088896f : 1.0f;
        #pragma unroll
        for (int mi = 0; mi < 4; mi++) {
            float4 bv = *(const float4*)&bias[fbase + mi * 16 + quad * 4];
            int dbase = mi * 16 + quad * 4;
            #pragma unroll
            for (int ni = 0; ni < 4; ni++) {
                int tok = (m0 & 1023) + wt * 64 + ni * 16 + l16;
                union { ushort4 v; unsigned u[2]; } pk;
                pk.u[0] = pack2((acc[mi][ni][0] + bv.x) * scale, (acc[mi][ni][1] + bv.y) * scale);
                pk.u[1] = pack2((acc[mi][ni][2] + bv.z) * scale, (acc[mi][ni][3] + bv.w) * scale);
                *(ushort4*)&dst[((size_t)bh * 1024 + tok) * 64 + dbase] = pk.v;
            }
        }
    } else {
        // -------- normal orientation for v (ushort4 into permuted-col vb) --------
        int wm = w >> 1, wn = w & 1;
        for (int k0 = 0; k0 < K; k0 += 64) {
            __syncthreads();
            #pragma unroll
            for (int r = 0; r < 4; r++) {
                int row = r * 32 + row0;
                int gc = k0 + ((ch ^ (row & 7)) << 3);
                gl_lds16(gA + (size_t)row * K + gc, As + r * 2048 + ((t >> 6) << 9));
                gl_lds16(gB + (size_t)row * K + gc, Bs + r * 2048 + ((t >> 6) << 9));
            }
            __syncthreads();
            #pragma unroll
            for (int ks = 0; ks < 2; ks++) {
                bf16x8 af[4], bf[4];
                #pragma unroll
                for (int mi = 0; mi < 4; mi++)
                    af[mi] = rd_sw(As, wm * 64 + mi * 16 + l16, ks * 4 + quad);
                #pragma unroll
                for (int ni = 0; ni < 4; ni++)
                    bf[ni] = rd_sw(Bs, wn * 64 + ni * 16 + l16, ks * 4 + quad);
                #pragma unroll
                for (int mi = 0; mi < 4; mi++)
                    #pragma unroll
                    for (int ni = 0; ni < 4; ni++)
                        acc[mi][ni] = __builtin_amdgcn_mfma_f32_16x16x32_bf16(af[mi], bf[ni], acc[mi][ni], 0, 0, 0);
            }
        }
        int nb = n0 + wn * 64;
        int h = (nb % 768) >> 6;
        int bh = bb * 12 + h;
        float bv[4];
        #pragma unroll
        for (int ni = 0; ni < 4; ni++) bv[ni] = bias[nb + ni * 16 + l16];
        #pragma unroll
        for (int mi = 0; mi < 4; mi++) {
            int nrow0 = (m0 & 1023) + wm * 64 + mi * 16 + quad * 4;
            // k-permuted column: key bits [n1 n0 q1 q0 c e] -> col bits [n1 q1 q0 n0 c e]
            int nl = nrow0 & 63;
            int ncol = (nrow0 & 960) + (nl & 32) + ((nl & 12) << 1) + ((nl & 16) >> 2);
            #pragma unroll
            for (int ni = 0; ni < 4; ni++) {
                int d = ni * 16 + l16;
                ushort4 pk;
                pk.x = f2bf(acc[mi][ni][0] + bv[ni]);
                pk.y = f2bf(acc[mi][ni][1] + bv[ni]);
                pk.z = f2bf(acc[mi][ni][2] + bv[ni]);
                pk.w = f2bf(acc[mi][ni][3] + bv[ni]);
                *(ushort4*)&vb[((size_t)bh * 64 + d) * 1024 + ncol] = pk;
            }
        }
    }
}

// ---------------- flash attention: 128 q/block, 32 q/wave, register-only P ----------------
// grid (96, 8): blockIdx.x = b*12+h fast dim -> one (b,h)'s q-blocks share an XCD L2.
// R6-measured 53 us configuration.
__global__ __launch_bounds__(256, 4)
void attn_kernel(const unsigned short* __restrict__ qb, const unsigned short* __restrict__ kb,
                 const unsigned short* __restrict__ vb,
                 unsigned short* __restrict__ attn) {
    __shared__ unsigned short Kt[2][4096];   // 64 keys x 64 d, swizzled
    __shared__ unsigned short Vt[2][4096];   // 64 d x 64 k(perm), swizzled
    int t = threadIdx.x, w = t >> 6, lane = t & 63, l16 = lane & 15, quad = lane >> 4;
    int bh = blockIdx.x, qblk = blockIdx.y;
    int bb = bh / 12, h = bh % 12;
    int qbase = qblk * 128 + w * 32;         // wave's 32-q base within (b,h)

    const unsigned short* kbase = kb + (size_t)bh * 65536;
    const unsigned short* vbase = vb + (size_t)bh * 65536;

    stage64(kbase, 64, Kt[0], t);
    stage64(vbase, 1024, Vt[0], t);

    // Q B-frags (pre-scaled by temp*log2e): qh in {0,1}, d-halves
    bf16x8 bq[2][2];
    #pragma unroll
    for (int qh = 0; qh < 2; qh++) {
        const unsigned short* qrow = qb + ((size_t)bh * 1024 + qbase + qh * 16 + l16) * 64;
        bq[qh][0] = *(const bf16x8*)&qrow[quad * 8];
        bq[qh][1] = *(const bf16x8*)&qrow[32 + quad * 8];
    }

    bf16x8 aone;
    #pragma unroll
    for (int j = 0; j < 8; j++) aone[j] = (short)0x3F80;   // bf16 1.0

    const f32x4 zero4 = {0.f, 0.f, 0.f, 0.f};
    f32x4 Oacc[2][4];     // [qh][ti] O^T: rows=d, cols=q
    f32x4 Osum[2];
    #pragma unroll
    for (int qh = 0; qh < 2; qh++) {
        Osum[qh] = zero4;
        #pragma unroll
        for (int ti = 0; ti < 4; ti++) Oacc[qh][ti] = zero4;
    }

    int ktd = qbase >> 6;                    // kt tile containing this wave's diagonal
    bool eq[4];
    #pragma unroll
    for (int i = 0; i < 4; i++) eq[i] = (l16 == quad * 4 + i);

    for (int kt = 0; kt < 16; kt++) {
        int cur = kt & 1;
        __syncthreads();                     // prefetch(kt) drained; prev reads done
        if (kt < 15) {
            stage64(kbase + (size_t)(kt + 1) * 4096, 64, Kt[cur ^ 1], t);
            stage64(vbase + (size_t)(kt + 1) * 64, 1024, Vt[cur ^ 1], t);
        }
        const unsigned short* Kc = Kt[cur];
        const unsigned short* Vc = Vt[cur];

        // S^T per ni (16 keys) x both q-halves; exp2 inline; pack straight into
        // the PV B-frag unions (registers only).
        union { unsigned u[4]; bf16x8 b; } pt[2][2];
        #pragma unroll
        for (int ni = 0; ni < 4; ni++) {
            bf16x8 ak0 = rd_sw(Kc, ni * 16 + l16, quad);
            bf16x8 ak1 = rd_sw(Kc, ni * 16 + l16, 4 + quad);
            #pragma unroll
            for (int qh = 0; qh < 2; qh++) {
                f32x4 z = zero4;
                z = __builtin_amdgcn_mfma_f32_16x16x32_bf16(ak0, bq[qh][0], z, 0, 0, 0);
                z = __builtin_amdgcn_mfma_f32_16x16x32_bf16(ak1, bq[qh][1], z, 0, 0, 0);
                float p0 = exp2f(z[0]);
                float p1 = exp2f(z[1]);
                float p2 = exp2f(z[2]);
                float p3 = exp2f(z[3]);
                if (kt == ktd && ni == ((w * 2 + qh) & 3)) {   // diagonal slice (uniform branch)
                    if (eq[0]) p0 = 0.f;
                    if (eq[1]) p1 = 0.f;
                    if (eq[2]) p2 = 0.f;
                    if (eq[3]) p3 = 0.f;
                }
                pt[qh][ni >> 1].u[(ni & 1) * 2 + 0] = pack2(p0, p1);
                pt[qh][ni >> 1].u[(ni & 1) * 2 + 1] = pack2(p2, p3);
            }
        }

        #pragma unroll
        for (int qh = 0; qh < 2; qh++) {
            // denominator: ones x P^T (permutation-invariant)
            Osum[qh] = __builtin_amdgcn_mfma_f32_16x16x32_bf16(aone, pt[qh][0].b, Osum[qh], 0, 0, 0);
            Osum[qh] = __builtin_amdgcn_mfma_f32_16x16x32_bf16(aone, pt[qh][1].b, Osum[qh], 0, 0, 0);
        }

        // O^T += V^T P^T  (V columns pre-permuted to k-order)
        #pragma unroll
        for (int ti = 0; ti < 4; ti++) {
            bf16x8 av0 = rd_sw(Vc, ti * 16 + l16, quad);
            bf16x8 av1 = rd_sw(Vc, ti * 16 + l16, 4 + quad);
            #pragma unroll
            for (int qh = 0; qh < 2; qh++) {
                Oacc[qh][ti] = __builtin_amdgcn_mfma_f32_16x16x32_bf16(av0, pt[qh][0].b, Oacc[qh][ti], 0, 0, 0);
                Oacc[qh][ti] = __builtin_amdgcn_mfma_f32_16x16x32_bf16(av1, pt[qh][1].b, Oacc[qh][ti], 0, 0, 0);
            }
        }
    }

    // epilogue: lane holds q=l16 (per qh), d = ti*16 + quad*4 + i -> ushort4 stores
    #pragma unroll
    for (int qh = 0; qh < 2; qh++) {
        float inv = 1.0f / Osum[qh][0];
        int orow = bb * 1024 + qbase + qh * 16 + l16;
        #pragma unroll
        for (int ti = 0; ti < 4; ti++) {
            union { ushort4 v; unsigned u[2]; } pk4;
            pk4.u[0] = pack2(Oacc[qh][ti][0] * inv, Oacc[qh][ti][1] * inv);
            pk4.u[1] = pack2(Oacc[qh][ti][2] * inv, Oacc[qh][ti][3] * inv);
            int col = h * 64 + ti * 16 + quad * 4;
            *(ushort4*)&attn[(size_t)orow * 768 + col] = pk4.v;
        }
    }
}

// ---------------- proj GEMM: (8192x768)@(768x768) + bias -> fp32 out ----------------
__global__ __launch_bounds__(256, 2)
void gemm_proj(const unsigned short* __restrict__ ab, const unsigned short* __restrict__ wT,
               const float* __restrict__ bias, float* __restrict__ out) {
    const int K = 768;
    __shared__ unsigned short As[8192];
    __shared__ unsigned short Bs[8192];
    int t = threadIdx.x;
    int m0 = blockIdx.x * 128;
    int n0 = blockIdx.y * 128;
    int w = t >> 6, lane = t & 63, l16 = lane & 15, quad = lane >> 4;
    int wm = w >> 1, wn = w & 1;
    const f32x4 zero4 = {0.f, 0.f, 0.f, 0.f};
    f32x4 acc[4][4];
    #pragma unroll
    for (int a = 0; a < 4; a++)
        #pragma unroll
        for (int b = 0; b < 4; b++) acc[a][b] = zero4;

    int row0 = t >> 3, ch = t & 7;
    const unsigned short* gA = ab + (size_t)m0 * K;
    const unsigned short* gB = wT + (size_t)n0 * K;

    for (int k0 = 0; k0 < K; k0 += 64) {
        __syncthreads();
        #pragma unroll
        for (int r = 0; r < 4; r++) {
            int row = r * 32 + row0;
            int gc = k0 + ((ch ^ (row & 7)) << 3);
            gl_lds16(gA + (size_t)row * K + gc, As + r * 2048 + ((t >> 6) << 9));
            gl_lds16(gB + (size_t)row * K + gc, Bs + r * 2048 + ((t >> 6) << 9));
        }
        __syncthreads();
        #pragma unroll
        for (int ks = 0; ks < 2; ks++) {
            bf16x8 af[4], bf[4];
            #pragma unroll
            for (int mi = 0; mi < 4; mi++)
                af[mi] = rd_sw(As, wm * 64 + mi * 16 + l16, ks * 4 + quad);
            #pragma unroll
            for (int ni = 0; ni < 4; ni++)
                bf[ni] = rd_sw(Bs, wn * 64 + ni * 16 + l16, ks * 4 + quad);
            #pragma unroll
            for (int mi = 0; mi < 4; mi++)
                #pragma unroll
                for (int ni = 0; ni < 4; ni++)
                    acc[mi][ni] = __builtin_amdgcn_mfma_f32_16x16x32_bf16(af[mi], bf[ni], acc[mi][ni], 0, 0, 0);
        }
    }

    #pragma unroll
    for (int mi = 0; mi < 4; mi++)
        #pragma unroll
        for (int i = 0; i < 4; i++) {
            int row = m0 + wm * 64 + mi * 16 + quad * 4 + i;
            float* orow = out + (size_t)row * 768;
            #pragma unroll
            for (int ni = 0; ni < 4; ni++) {
                int col = n0 + wn * 64 + ni * 16 + l16;
                orow[col] = acc[mi][ni][i] + bias[col];
            }
        }
}

extern "C" void kernel_launch(void* const* d_in, const int* in_sizes, int n_in,
                              void* d_out, int out_size, void* d_ws, size_t ws_size,
                              hipStream_t stream) {
    const float* x      = (const float*)d_in[0];
    const float* w_qkv  = (const float*)d_in[1];
    const float* b_qkv  = (const float*)d_in[2];
    const float* w_proj = (const float*)d_in[3];
    const float* b_proj = (const float*)d_in[4];
    const float* temp   = (const float*)d_in[5];
    float* out = (float*)d_out;

    char* ws = (char*)d_ws;
    unsigned short* xb     = (unsigned short*)(ws);                 // 8192x768 bf16
    unsigned short* wqkvT  = (unsigned short*)(ws + 12582912);      // 2304x768 bf16
    unsigned short* wprojT = (unsigned short*)(ws + 16121856);      // 768x768 bf16
    unsigned short* qb     = (unsigned short*)(ws + 17301504);      // (B H N D) bf16, pre-scaled
    unsigned short* kb     = (unsigned short*)(ws + 29884416);      // (B H N D) bf16
    unsigned short* vb     = (unsigned short*)(ws + 42467328);      // (B H D N) bf16, k-permuted cols
    unsigned short* attn   = (unsigned short*)(ws + 55050240);      // 8192x768 bf16

    prep<<<6720, 256, 0, stream>>>(x, w_qkv, w_proj, xb, wqkvT, wprojT);
    gemm_qkv<<<dim3(64, 18), 256, 0, stream>>>(xb, wqkvT, b_qkv, temp, qb, kb, vb);
    attn_kernel<<<dim3(96, 8), 256, 0, stream>>>(qb, kb, vb, attn);
    gemm_proj<<<dim3(64, 6), 256, 0, stream>>>(attn, wprojT, b_proj, out);
}